// Round 4
// baseline (170.582 us; speedup 1.0000x reference)
//
#include <hip/hip_runtime.h>
#include <stdint.h>

typedef unsigned short u16;
typedef __attribute__((ext_vector_type(8))) __bf16 bf16x8;
typedef __attribute__((ext_vector_type(4))) float f32x4;
typedef __attribute__((ext_vector_type(4))) u16 u16x4;
typedef __attribute__((ext_vector_type(8))) u16 u16x8;

#define N_IMG 64
#define C_IN  64
#define HW_IN 3136   // 56*56
#define W_IN  56
#define C_OUT 128
#define OH    54
#define OW    54
#define SPI   2916   // 54*54
#define KTOT  576    // C_IN*9
#define NBPI  23     // ceil(SPI/128) blocks per image
#define NWG   (N_IMG*NBPI)   // 1472
#define SLAB_POS 256 // slab rows (input positions), 32 KB

typedef __attribute__((address_space(3))) unsigned int lds_uint;
typedef __attribute__((address_space(1))) unsigned int gbl_uint;

__device__ __forceinline__ void load16_to_lds(const u16* g, u16* l) {
  // lane i of the wave writes LDS base + i*16 bytes; g is per-lane.
  __builtin_amdgcn_global_load_lds((const gbl_uint*)g, (lds_uint*)l, 16, 0, 0);
}

__device__ inline u16 f32_bf16_rne(float f) {
  unsigned u = __float_as_uint(f);
  u = (u + 0x7FFFu + ((u >> 16) & 1u)) >> 16;
  return (u16)u;
}

// Merged converter (unchanged from round 3).
__global__ __launch_bounds__(256) void convert_xw(
    const float* __restrict__ x, const float* __restrict__ w,
    u16* __restrict__ xt, u16* __restrict__ wtT)
{
  if (blockIdx.y == N_IMG) {
    int o = blockIdx.x * 256 + threadIdx.x;
    for (; o < C_OUT * KTOT; o += 49 * 256) {
      int co = o / KTOT;
      int k  = o - co * KTOT;
      int t  = k >> 6;       // kh*3+kw
      int ci = k & 63;
      wtT[o] = f32_bf16_rne(w[co * KTOT + ci * 9 + t]);
    }
    return;
  }

  __shared__ u16 tile[64][68];
  int n  = blockIdx.y;
  int s0 = blockIdx.x * 64;
  int t  = threadIdx.x;

  int r = t >> 2;
  int q = t & 3;
  const float* xp = x + (size_t)n * C_IN * HW_IN + (size_t)r * HW_IN + s0 + q * 16;
  #pragma unroll
  for (int j = 0; j < 4; j++) {
    f32x4 v = *(const f32x4*)(xp + 4 * j);
    u16x4 o4;
    #pragma unroll
    for (int e = 0; e < 4; e++) {
      float f = fminf(fmaxf(v[e], -128.f), 127.f);
      int iv = (int)f;
      o4[e] = f32_bf16_rne((float)iv);
    }
    *(u16x4*)&tile[r][q * 16 + 4 * j] = o4;
  }
  __syncthreads();

  u16* op = xt + ((size_t)n * HW_IN + s0) * C_IN;
  int g = t & 7;
  int m = t >> 3;
  #pragma unroll
  for (int k2 = 0; k2 < 2; k2++) {
    int sp = m * 2 + k2;
    u16x8 o8;
    #pragma unroll
    for (int c = 0; c < 8; c++) o8[c] = tile[g * 8 + c][sp];
    *(u16x8*)&op[(size_t)sp * C_IN + g * 8] = o8;
  }
}

// Implicit GEMM with HALO-SLAB pixel staging.
// Block = 128 consecutive output positions of ONE image x 128 cout, 8 waves.
// All 9 taps of the 3x3 conv read the SAME slab of <=248 contiguous input
// positions (xt is [img][i][ci], i = oh_in*56 + ow_in): tap (kh,kw) is just a
// row offset kh*56+kw into the slab. Pixels are staged ONCE (32 KB, coalesced,
// source-pre-swizzled so linear global_load_lds yields XOR-swizzled rows) and
// read barrier-free for all 9 chunks. Only W (16 KB/tap, L2-resident) keeps the
// double-buffered 1-barrier pipeline. P staging traffic drops 9x147KB -> 32KB
// per block (~4.6x less L3 traffic -> attacks the L3-BW bound).
__global__ __launch_bounds__(512, 4) void conv_gemm(
    const u16* __restrict__ xt, const u16* __restrict__ wtT,
    const float* __restrict__ bias, float* __restrict__ y)
{
  __shared__ u16 slab[SLAB_POS * 64];   // 32 KB pixel slab (swizzled ci-groups)
  __shared__ u16 sW[2][128 * 64];       // 2 x 16 KB weight dbuf

  int tid  = threadIdx.x;
  int wv   = tid >> 6;           // 0..7
  int lane = tid & 63;
  int ln   = lane & 15;
  int q    = lane >> 4;
  int wy   = wv >> 1;            // cout quarter (32 rows)
  int wx   = wv & 1;             // spatial half (64 cols)
  int l7   = ln & 7;

  // XCD-aware bijective swizzle: 1472 = 8*184
  int b  = blockIdx.x;
  int wg = (b & 7) * (NWG / 8) + (b >> 3);
  int img = wg / NBPI;
  int cb  = wg - img * NBPI;
  int r0  = cb * 128;                    // first output position (image-local)
  int ibase = r0 + 2 * (r0 / OW);        // slab base input position

  const u16* xg = xt + ((size_t)img * HW_IN + ibase) * C_IN;

  // ---- weight staging addrs (lane -> row r8, 16B-group cg, swizzle cg^r8) ----
  int r8 = lane >> 3;
  int cg = lane & 7;
  int scol = (cg ^ r8) * 8;
  int wt_off[2];
  #pragma unroll
  for (int j = 0; j < 2; j++)
    wt_off[j] = (wv * 16 + j * 8 + r8) * KTOT + scol;

  // ---- slab staging: 4 rounds x 512 threads x 16 B = 32 KB ----
  // LDS is written linearly (slot = j*512 + tid); the SOURCE address carries the
  // inverse swizzle so that LDS[row][colg] = xt[row][colg ^ (row&7)].
  int slab_src[4];
  #pragma unroll
  for (int j = 0; j < 4; j++) {
    int slot = j * 512 + tid;
    int row  = slot >> 3, cgc = slot & 7;
    slab_src[j] = row * 64 + ((cgc ^ (row & 7)) * 8);
  }

  f32x4 acc[2][4];
  #pragma unroll
  for (int mt = 0; mt < 2; mt++)
    #pragma unroll
    for (int nt = 0; nt < 4; nt++)
      acc[mt][nt] = (f32x4){0.f, 0.f, 0.f, 0.f};

  // per-lane output positions and their slab base rows (tap (0,0))
  int prel[4], rbase[4];
  #pragma unroll
  for (int nt = 0; nt < 4; nt++) {
    int pr = r0 + wx * 64 + nt * 16 + ln;
    prel[nt]  = pr;
    rbase[nt] = pr + 2 * (pr / OW) - ibase;   // 0..133
  }
  int wrow[2];
  #pragma unroll
  for (int i = 0; i < 2; i++) wrow[i] = (wy * 32 + i * 16 + ln) * 64;

  // ---- prologue: stage slab + W tap 0 ----
  #pragma unroll
  for (int j = 0; j < 4; j++)
    load16_to_lds(xg + slab_src[j], slab + (size_t)(j * 512 + wv * 64) * 8);
  #pragma unroll
  for (int j = 0; j < 2; j++)
    load16_to_lds(wtT + wt_off[j], &sW[0][(wv * 16 + j * 8) * 64]);

  #pragma unroll
  for (int kc = 0; kc < 9; kc++) {
    const int cur = kc & 1, nxt = cur ^ 1;
    const int kh = kc / 3, kw = kc - kh * 3;
    const int koff = kh * W_IN + kw;         // slab row offset of this tap

    // drains vmcnt(0)+lgkmcnt(0): slab + W[cur] landed; reads of W[nxt] retired.
    __syncthreads();

    if (kc < 8) {   // prefetch next tap's weights; flies during the MFMA below
      #pragma unroll
      for (int j = 0; j < 2; j++)
        load16_to_lds(wtT + wt_off[j] + (kc + 1) * 64, &sW[nxt][(wv * 16 + j * 8) * 64]);
    }

    #pragma unroll
    for (int s = 0; s < 2; s++) {
      int g = s * 4 + q;                     // ci 8-group within the tap
      int pgW = (g ^ l7) * 8;
      bf16x8 wf[2], pf[4];
      #pragma unroll
      for (int mt = 0; mt < 2; mt++)
        wf[mt] = *(const bf16x8*)(&sW[cur][0] + wrow[mt] + pgW);
      #pragma unroll
      for (int nt = 0; nt < 4; nt++) {
        int rb = rbase[nt] + koff;           // slab row for this lane+tap
        pf[nt] = *(const bf16x8*)(slab + rb * 64 + ((g ^ (rb & 7)) * 8));
      }
      #pragma unroll
      for (int mt = 0; mt < 2; mt++)
        #pragma unroll
        for (int nt = 0; nt < 4; nt++)
          acc[mt][nt] = __builtin_amdgcn_mfma_f32_16x16x32_bf16(
              wf[mt], pf[nt], acc[mt][nt], 0, 0, 0);
    }
  }

  // epilogue: y is [img][co][p_rel]; mask the tail block's dead positions
  size_t obase0 = (size_t)img * C_OUT * SPI;
  #pragma unroll
  for (int nt = 0; nt < 4; nt++) {
    int pr = prel[nt];
    if (pr < SPI) {
      #pragma unroll
      for (int mt = 0; mt < 2; mt++) {
        int co0 = wy * 32 + mt * 16 + q * 4;
        #pragma unroll
        for (int r = 0; r < 4; r++)
          y[obase0 + (size_t)(co0 + r) * SPI + pr] = acc[mt][nt][r] + bias[co0 + r];
      }
    }
  }
}

extern "C" void kernel_launch(void* const* d_in, const int* in_sizes, int n_in,
                              void* d_out, int out_size, void* d_ws, size_t ws_size,
                              hipStream_t stream) {
  const float* x    = (const float*)d_in[0];
  const float* w    = (const float*)d_in[1];
  const float* bias = (const float*)d_in[2];
  float* y = (float*)d_out;

  u16* wtT = (u16*)d_ws;
  u16* xt  = (u16*)((char*)d_ws + (size_t)C_OUT * KTOT * sizeof(u16)); // +147456 B

  hipLaunchKernelGGL(convert_xw, dim3(HW_IN / 64, N_IMG + 1), dim3(256), 0, stream,
                     x, w, xt, wtT);
  hipLaunchKernelGGL(conv_gemm, dim3(NWG), dim3(512), 0, stream,
                     xt, wtT, bias, y);
}